// Round 5
// baseline (216.791 us; speedup 1.0000x reference)
//
#include <hip/hip_runtime.h>

// Problem constants (from reference)
#define BATCH 16384
#define CNUM  8
#define DIN   256
#define NH0   512
#define NH1   256

#define BT       64            // batch rows per block
#define NTHREADS 512           // 8 waves

#define X_ELEMS  (BATCH * DIN)        // 4194304
#define W0_ELEMS (CNUM * NH0 * DIN)   // 1048576
#define W1_ELEMS (CNUM * NH1 * NH0)   // 1048576
#define WS_NEED  ((size_t)(X_ELEMS + W0_ELEMS + W1_ELEMS) * 2)  // 12.6 MB bf16

typedef __bf16 bf16x8 __attribute__((ext_vector_type(8)));
typedef __bf16 bf16x4 __attribute__((ext_vector_type(4)));
typedef float  f32x4  __attribute__((ext_vector_type(4)));
typedef float  f32x8  __attribute__((ext_vector_type(8)));
typedef float  f32x16 __attribute__((ext_vector_type(16)));

// ---------------------------------------------------------------------------
// Prep: fp32 -> bf16 for x, W0, W1 into ws.  786432 chunks x 8 elems.
// ---------------------------------------------------------------------------
__global__ __launch_bounds__(256)
void cvt_bf16(const float* __restrict__ x, const float* __restrict__ W0,
              const float* __restrict__ W1, __bf16* __restrict__ ws) {
    const int i = blockIdx.x * 256 + threadIdx.x;   // chunk of 8 elems
    const float* src;
    __bf16* dst;
    int off;
    if (i < X_ELEMS / 8)                 { src = x;  dst = ws;                        off = i * 8; }
    else if (i < (X_ELEMS + W0_ELEMS)/8) { src = W0; dst = ws + X_ELEMS;             off = (i - X_ELEMS/8) * 8; }
    else                                 { src = W1; dst = ws + X_ELEMS + W0_ELEMS;  off = (i - (X_ELEMS + W0_ELEMS)/8) * 8; }
    f32x8 v = *(const f32x8*)(src + off);
    bf16x8 r;
    #pragma unroll
    for (int j = 0; j < 8; ++j) r[j] = (__bf16)v[j];
    *(bf16x8*)(dst + off) = r;
}

// ---------------------------------------------------------------------------
// Main fused kernel (bf16, 32x32x16 MFMA).
// grid = (BATCH/BT)*CNUM; c = blockIdx&7 (XCD round-robin -> W[c] L2-resident).
//
// 32-format LDS granules (1 KB = 16k x 32m bf16): value (m, k) lives at
//   granule g = (k>>4)*2 + (m>>5), elem = ((m&31) + 32*((k>>3)&1))*8 + (k&7).
// Property: MFMA B-frag read for k-step ks, m-tile mt is
//   base + (ks*2+mt)*512 + lane*8  -> lane-contiguous b128, conflict-free.
// h0s holds 64 granules (64 KB, m=64 x k=512); xs (x tile, m=64 x k=256,
// 32 granules) aliases its upper 32 KB during layer 0.
//
// Layer 0: wave w computes n-slice w*64..+63 (2 n-tiles x 2 m-tiles,
//   acc = 4 x f32x16 = 64 VGPRs), K = 256 in 16 steps. One phase, 1 barrier.
// Epilogue: bias+relu+cvt, 16 b64 writes/wave (verified 4 acc/bank = free).
// Layer 1: wave w computes o-slice w*32..+31 x m=64 (2 tiles), K=512 in 32
//   steps. Layer 2: in-register dot + shfl_xor(32) + LDS 8-wave reduce.
// ---------------------------------------------------------------------------
__global__ __launch_bounds__(NTHREADS, 4)
void confounder_main(const __bf16* __restrict__ ws,
                     const float* __restrict__ b0,
                     const float* __restrict__ b1,
                     const float* __restrict__ W2,
                     const float* __restrict__ b2,
                     float* __restrict__ out) {
    __shared__ __align__(16) __bf16 h0s[BT * NH0];  // 64 KB, 32-format granules
    __shared__ float red[8][BT];                    // 2 KB
    __bf16* xs = h0s + 32 * 512;                    // upper 32 KB alias for x tile

    const __bf16* xbf = ws;
    const __bf16* w0b = ws + X_ELEMS;
    const __bf16* w1b = ws + X_ELEMS + W0_ELEMS;

    const int c    = blockIdx.x & 7;
    const int mb   = blockIdx.x >> 3;
    const int row0 = mb * BT;

    const int tid  = threadIdx.x;
    const int w    = tid >> 6;    // wave 0..7
    const int lane = tid & 63;
    const int l31  = lane & 31;
    const int l5   = lane >> 5;   // 0..1

    // ---- stage x tile into LDS (32-format), row = lane gather -------------
    // q: kc = q*8 + w (8-elem k-chunk), row = lane. LDS write is the
    // lane-contiguous-16B pattern (2-way on l5 halves = free).
    #pragma unroll
    for (int q = 0; q < 4; ++q) {
        const int kc = q * 8 + w;             // 0..31
        bf16x8 v = *(const bf16x8*)(xbf + (size_t)(row0 + lane) * DIN + kc * 8);
        *(bf16x8*)(xs + ((kc >> 1) * 2 + (lane >> 5)) * 512 + ((lane & 31) + 32 * (kc & 1)) * 8) = v;
    }
    __syncthreads();

    // ================= Layer 0:  h0[n = w*64..+63][m 0..63] =================
    // A = W0 rows (n), B = x (cols m).  A: row=l31, k=8*l5+j. B: col=l31, same k.
    f32x16 acc0[2][2];   // [nt][mt] 64 regs
    #pragma unroll
    for (int nt = 0; nt < 2; ++nt)
        #pragma unroll
        for (int mt = 0; mt < 2; ++mt)
            #pragma unroll
            for (int r = 0; r < 16; ++r)
                acc0[nt][mt][r] = 0.f;

    const __bf16* w0r = w0b + ((size_t)c * NH0 + w * 64 + l31) * DIN + 8 * l5;

    #pragma unroll
    for (int ks = 0; ks < 16; ++ks) {         // K = 256, 16 steps of 16
        bf16x8 a0 = *(const bf16x8*)(w0r + ks * 16);
        bf16x8 a1 = *(const bf16x8*)(w0r + 32 * DIN + ks * 16);
        bf16x8 bA = *(const bf16x8*)(xs + (ks * 2 + 0) * 512 + lane * 8);
        bf16x8 bB = *(const bf16x8*)(xs + (ks * 2 + 1) * 512 + lane * 8);
        __builtin_amdgcn_s_setprio(1);
        acc0[0][0] = __builtin_amdgcn_mfma_f32_32x32x16_bf16(a0, bA, acc0[0][0], 0, 0, 0);
        acc0[0][1] = __builtin_amdgcn_mfma_f32_32x32x16_bf16(a0, bB, acc0[0][1], 0, 0, 0);
        acc0[1][0] = __builtin_amdgcn_mfma_f32_32x32x16_bf16(a1, bA, acc0[1][0], 0, 0, 0);
        acc0[1][1] = __builtin_amdgcn_mfma_f32_32x32x16_bf16(a1, bB, acc0[1][1], 0, 0, 0);
        __builtin_amdgcn_s_setprio(0);
    }

    // prefetch W1 ks=0 (rides through the barrier + epilogue)
    const __bf16* w1r = w1b + ((size_t)c * NH1 + w * 32 + l31) * NH0 + 8 * l5;
    bf16x8 qa = *(const bf16x8*)(w1r);

    __syncthreads();   // all xs reads done before h0s (incl. upper half) write

    // ---- epilogue: C row n = w*64 + nt*32 + r + 8q + 4*l5, col m = mt*32+l31.
    // write (m, k=n) -> granule (w*4 + nt*2 + (q>>1))*2 + mt,
    //                   elem l31*8 + (q&1)*256 + l5*4 (+r)
    #pragma unroll
    for (int nt = 0; nt < 2; ++nt) {
        #pragma unroll
        for (int q = 0; q < 4; ++q) {
            const int nb = w * 64 + nt * 32 + 8 * q + 4 * l5;
            const f32x4 b4 = *(const f32x4*)(b0 + c * NH0 + nb);
            #pragma unroll
            for (int mt = 0; mt < 2; ++mt) {
                bf16x4 pk;
                #pragma unroll
                for (int r = 0; r < 4; ++r) {
                    float v = acc0[nt][mt][q * 4 + r] + b4[r];
                    v = v > 0.f ? v : 0.f;
                    pk[r] = (__bf16)v;
                }
                const int g = (w * 4 + nt * 2 + (q >> 1)) * 2 + mt;
                *(bf16x4*)(h0s + g * 512 + l31 * 8 + (q & 1) * 256 + l5 * 4) = pk;
            }
        }
    }
    __syncthreads();   // h0 complete

    // ================= Layer 1:  h1[o = w*32..+31][m 0..63] =================
    f32x16 acc1[2];    // [mt] 32 regs
    #pragma unroll
    for (int mt = 0; mt < 2; ++mt)
        #pragma unroll
        for (int r = 0; r < 16; ++r)
            acc1[mt][r] = 0.f;

    bf16x8 a = qa;
    #pragma unroll
    for (int ks = 0; ks < 32; ++ks) {         // K = 512, 32 steps of 16
        bf16x8 na = a;
        if (ks < 31) na = *(const bf16x8*)(w1r + (ks + 1) * 16);
        bf16x8 bA = *(const bf16x8*)(h0s + (ks * 2 + 0) * 512 + lane * 8);
        bf16x8 bB = *(const bf16x8*)(h0s + (ks * 2 + 1) * 512 + lane * 8);
        __builtin_amdgcn_s_setprio(1);
        acc1[0] = __builtin_amdgcn_mfma_f32_32x32x16_bf16(a, bA, acc1[0], 0, 0, 0);
        acc1[1] = __builtin_amdgcn_mfma_f32_32x32x16_bf16(a, bB, acc1[1], 0, 0, 0);
        __builtin_amdgcn_s_setprio(0);
        a = na;
    }

    // ================= Layer 2 ==============================================
    // acc1[mt]: o = w*32 + r + 8q + 4*l5, m = mt*32 + l31
    float part[2] = {0.f, 0.f};
    #pragma unroll
    for (int q = 0; q < 4; ++q) {
        const int ob = w * 32 + 8 * q + 4 * l5;
        const f32x4 b1v = *(const f32x4*)(b1 + c * NH1 + ob);
        const f32x4 w2v = *(const f32x4*)(W2 + c * NH1 + ob);
        #pragma unroll
        for (int mt = 0; mt < 2; ++mt) {
            #pragma unroll
            for (int r = 0; r < 4; ++r) {
                float v = acc1[mt][q * 4 + r] + b1v[r];
                v = v > 0.f ? v : 0.f;
                part[mt] += v * w2v[r];
            }
        }
    }
    #pragma unroll
    for (int mt = 0; mt < 2; ++mt)
        part[mt] += __shfl_xor(part[mt], 32, 64);   // fold l5 halves (o groups)
    if (l5 == 0) {
        #pragma unroll
        for (int mt = 0; mt < 2; ++mt)
            red[w][mt * 32 + l31] = part[mt];
    }
    __syncthreads();

    if (tid < BT) {
        float s = 0.f;
        #pragma unroll
        for (int ww = 0; ww < 8; ++ww) s += red[ww][tid];
        s += b2[c];
        out[(size_t)(row0 + tid) * CNUM + c] = s;
    }
}

// ---------------------------------------------------------------------------
// Fallback (fp32 loads, no workspace) in case ws_size < WS_NEED. BT=64 geom.
// ---------------------------------------------------------------------------
__device__ __forceinline__ bf16x8 ld_cvt8(const float* __restrict__ p) {
    f32x8 v = *(const f32x8*)p;
    bf16x8 r;
    #pragma unroll
    for (int i = 0; i < 8; ++i) r[i] = (__bf16)v[i];
    return r;
}

#define P0 (NH0 + 8)

__global__ __launch_bounds__(NTHREADS, 4)
void confounder_fused(const float* __restrict__ x,
                      const float* __restrict__ W0,
                      const float* __restrict__ b0,
                      const float* __restrict__ W1,
                      const float* __restrict__ b1,
                      const float* __restrict__ W2,
                      const float* __restrict__ b2,
                      float* __restrict__ out) {
    __shared__ __align__(16) __bf16 h0s[BT * P0];
    __shared__ float red[8][BT];

    const int c    = blockIdx.x & 7;
    const int mb   = blockIdx.x >> 3;
    const int row0 = mb * BT;
    const int tid  = threadIdx.x;
    const int w    = tid >> 6;
    const int lane = tid & 63;
    const int l15  = lane & 15;
    const int l4   = lane >> 4;

    f32x4 acc0[4][4];
    #pragma unroll
    for (int mt = 0; mt < 4; ++mt)
        #pragma unroll
        for (int nt = 0; nt < 4; ++nt)
            acc0[mt][nt] = (f32x4){0.f, 0.f, 0.f, 0.f};

    const float* xb  = x  + (size_t)(row0 + l15) * DIN + 8 * l4;
    const float* w0b = W0 + ((size_t)c * NH0 + w * 64 + l15) * DIN + 8 * l4;

    #pragma unroll
    for (int ks = 0; ks < DIN / 32; ++ks) {
        bf16x8 a[4];
        #pragma unroll
        for (int mt = 0; mt < 4; ++mt)
            a[mt] = ld_cvt8(xb + mt * 16 * DIN + ks * 32);
        #pragma unroll
        for (int nt = 0; nt < 4; ++nt) {
            bf16x8 bf = ld_cvt8(w0b + nt * 16 * DIN + ks * 32);
            #pragma unroll
            for (int mt = 0; mt < 4; ++mt)
                acc0[mt][nt] = __builtin_amdgcn_mfma_f32_16x16x32_bf16(a[mt], bf, acc0[mt][nt], 0, 0, 0);
        }
    }
    #pragma unroll
    for (int nt = 0; nt < 4; ++nt) {
        const int n    = (w * 4 + nt) * 16 + l15;
        const float bv = b0[c * NH0 + n];
        #pragma unroll
        for (int mt = 0; mt < 4; ++mt)
            #pragma unroll
            for (int r = 0; r < 4; ++r) {
                float v = acc0[mt][nt][r] + bv;
                v = v > 0.f ? v : 0.f;
                h0s[(mt * 16 + l4 * 4 + r) * P0 + n] = (__bf16)v;
            }
    }
    __syncthreads();

    f32x4 acc1[2][4];
    #pragma unroll
    for (int ot = 0; ot < 2; ++ot)
        #pragma unroll
        for (int nt = 0; nt < 4; ++nt)
            acc1[ot][nt] = (f32x4){0.f, 0.f, 0.f, 0.f};

    const float* w1b = W1 + ((size_t)c * NH1 + w * 32 + l15) * NH0 + 8 * l4;

    #pragma unroll
    for (int ks = 0; ks < NH0 / 32; ++ks) {
        bf16x8 a[2];
        #pragma unroll
        for (int ot = 0; ot < 2; ++ot)
            a[ot] = ld_cvt8(w1b + ot * 16 * NH0 + ks * 32);
        #pragma unroll
        for (int nt = 0; nt < 4; ++nt) {
            bf16x8 bf = *(const bf16x8*)(&h0s[(nt * 16 + l15) * P0 + ks * 32 + 8 * l4]);
            #pragma unroll
            for (int ot = 0; ot < 2; ++ot)
                acc1[ot][nt] = __builtin_amdgcn_mfma_f32_16x16x32_bf16(a[ot], bf, acc1[ot][nt], 0, 0, 0);
        }
    }

    float part[4] = {0.f, 0.f, 0.f, 0.f};
    #pragma unroll
    for (int ot = 0; ot < 2; ++ot)
        #pragma unroll
        for (int r = 0; r < 4; ++r) {
            const int o     = (2 * w + ot) * 16 + l4 * 4 + r;
            const float b1v = b1[c * NH1 + o];
            const float w2v = W2[c * NH1 + o];
            #pragma unroll
            for (int nt = 0; nt < 4; ++nt) {
                float v = acc1[ot][nt][r] + b1v;
                v = v > 0.f ? v : 0.f;
                part[nt] += v * w2v;
            }
        }
    #pragma unroll
    for (int nt = 0; nt < 4; ++nt) {
        part[nt] += __shfl_xor(part[nt], 16, 64);
        part[nt] += __shfl_xor(part[nt], 32, 64);
    }
    if (l4 == 0) {
        #pragma unroll
        for (int nt = 0; nt < 4; ++nt)
            red[w][nt * 16 + l15] = part[nt];
    }
    __syncthreads();

    if (tid < BT) {
        float s = 0.f;
        #pragma unroll
        for (int ww = 0; ww < 8; ++ww) s += red[ww][tid];
        s += b2[c];
        out[(size_t)(row0 + tid) * CNUM + c] = s;
    }
}

extern "C" void kernel_launch(void* const* d_in, const int* in_sizes, int n_in,
                              void* d_out, int out_size, void* d_ws, size_t ws_size,
                              hipStream_t stream) {
    const float* x  = (const float*)d_in[0];
    const float* W0 = (const float*)d_in[1];
    const float* b0 = (const float*)d_in[2];
    const float* W1 = (const float*)d_in[3];
    const float* b1 = (const float*)d_in[4];
    const float* W2 = (const float*)d_in[5];
    const float* b2 = (const float*)d_in[6];
    float* out = (float*)d_out;

    if (ws_size >= WS_NEED) {
        __bf16* ws = (__bf16*)d_ws;
        cvt_bf16<<<dim3((X_ELEMS + W0_ELEMS + W1_ELEMS) / 8 / 256), dim3(256), 0, stream>>>(x, W0, W1, ws);
        confounder_main<<<dim3((BATCH / BT) * CNUM), dim3(NTHREADS), 0, stream>>>(ws, b0, b1, W2, b2, out);
    } else {
        confounder_fused<<<dim3((BATCH / BT) * CNUM), dim3(NTHREADS), 0, stream>>>(x, W0, b0, W1, b1, W2, b2, out);
    }
}

// Round 6
// 205.343 us; speedup vs baseline: 1.0558x; 1.0558x over previous
//
#include <hip/hip_runtime.h>

// Problem constants (from reference)
#define BATCH 16384
#define CNUM  8
#define DIN   256
#define NH0   512
#define NH1   256

#define BT       64            // batch rows per block
#define NTHREADS 512           // 8 waves

#define X_ELEMS  (BATCH * DIN)        // 4194304
#define W0_ELEMS (CNUM * NH0 * DIN)   // 1048576
#define W1_ELEMS (CNUM * NH1 * NH0)   // 1048576
#define WS_NEED  ((size_t)(X_ELEMS + W0_ELEMS + W1_ELEMS) * 2)  // 12.6 MB bf16

typedef __bf16 bf16x8 __attribute__((ext_vector_type(8)));
typedef __bf16 bf16x4 __attribute__((ext_vector_type(4)));
typedef float  f32x4  __attribute__((ext_vector_type(4)));
typedef float  f32x8  __attribute__((ext_vector_type(8)));

#define MFMA16(a, b, c) __builtin_amdgcn_mfma_f32_16x16x32_bf16((a), (b), (c), 0, 0, 0)

// ---------------------------------------------------------------------------
// Prep: fp32 -> bf16 for x, W0, W1 into ws.  786432 chunks x 8 elems.
// ---------------------------------------------------------------------------
__global__ __launch_bounds__(256)
void cvt_bf16(const float* __restrict__ x, const float* __restrict__ W0,
              const float* __restrict__ W1, __bf16* __restrict__ ws) {
    const int i = blockIdx.x * 256 + threadIdx.x;   // chunk of 8 elems
    const float* src;
    __bf16* dst;
    int off;
    if (i < X_ELEMS / 8)                 { src = x;  dst = ws;                        off = i * 8; }
    else if (i < (X_ELEMS + W0_ELEMS)/8) { src = W0; dst = ws + X_ELEMS;             off = (i - X_ELEMS/8) * 8; }
    else                                 { src = W1; dst = ws + X_ELEMS + W0_ELEMS;  off = (i - (X_ELEMS + W0_ELEMS)/8) * 8; }
    f32x8 v = *(const f32x8*)(src + off);
    bf16x8 r;
    #pragma unroll
    for (int j = 0; j < 8; ++j) r[j] = (__bf16)v[j];
    *(bf16x8*)(dst + off) = r;
}

// ---------------------------------------------------------------------------
// Main fused kernel (bf16, 16x16x32 MFMA, r4 skeleton + enforced load ring).
// grid = (BATCH/BT)*CNUM; c = blockIdx&7 (XCD round-robin -> W[c] L2-resident).
//
// LDS h0s = 64 granules x 512 elems (1 KB), granule g = (n>>8)*32 + bt*8 + kw
//   (bt = m>>4, kw = (n>>5)&7). Frag-major -> layer-1 ds_read_b128 is
//   lane-contiguous, conflict-free. xs aliases granules 32..63 during L0.
//
// UNIFIED 4-deep W-load ring aw[4][2] (static ks&3 indexing): half-0 pairs
// chain into half-1 pairs chain into W1 pairs -- 8 loads permanently in
// flight, surviving both barriers and both epilogues. One
// sched_barrier(0) per k-step pins each refill >=4 steps (~600 cyc) ahead
// of its consuming MFMA cluster (the compiler otherwise sinks the loads:
// rounds 0-5 all compiled to VGPR<=64 with just-in-time loads).
// ---------------------------------------------------------------------------
__global__ __launch_bounds__(NTHREADS, 4)
void confounder_main(const __bf16* __restrict__ ws,
                     const float* __restrict__ b0,
                     const float* __restrict__ b1,
                     const float* __restrict__ W2,
                     const float* __restrict__ b2,
                     float* __restrict__ out) {
    __shared__ __align__(16) __bf16 h0s[BT * NH0];  // 64 KB granule-major
    __shared__ float red[8][BT];                    // 2 KB
    __bf16* xs = h0s + 32 * 512;                    // upper 32 KB alias for x tile

    const __bf16* xbf = ws;
    const __bf16* w0b = ws + X_ELEMS;
    const __bf16* w1b = ws + X_ELEMS + W0_ELEMS;

    const int c    = blockIdx.x & 7;
    const int mb   = blockIdx.x >> 3;
    const int row0 = mb * BT;

    const int tid  = threadIdx.x;
    const int w    = tid >> 6;    // wave 0..7
    const int lane = tid & 63;
    const int l15  = lane & 15;
    const int l4   = lane >> 4;   // 0..3

    // ---- stage x tile into LDS (granules 32..63), frag-major --------------
    #pragma unroll
    for (int q = 0; q < 4; ++q) {
        const int p  = w * 4 + q;
        const int mt = p >> 3, ks = p & 7;
        bf16x8 v = *(const bf16x8*)(xbf + (size_t)(row0 + mt * 16 + l15) * DIN + ks * 32 + 8 * l4);
        *(bf16x8*)(xs + (p * 64 + lane) * 8) = v;
    }

    // W row bases
    const __bf16* w0r  = w0b + ((size_t)c * NH0 + w * 32 + l15) * DIN + 8 * l4;   // half 0
    const __bf16* w0r1 = w0r + 256 * DIN;                                         // half 1
    const __bf16* w1r  = w1b + ((size_t)c * NH1 + w * 32 + l15) * NH0 + 8 * l4;   // layer 1

    // ---- ring prologue: half-0 pairs 0..3, pinned before the barrier ------
    bf16x8 aw[4][2];
    #pragma unroll
    for (int kp = 0; kp < 4; ++kp) {
        aw[kp][0] = *(const bf16x8*)(w0r + kp * 32);
        aw[kp][1] = *(const bf16x8*)(w0r + 16 * DIN + kp * 32);
    }
    __builtin_amdgcn_sched_barrier(0);
    __syncthreads();

    f32x4 acc[2][4];   // [at][bt]
    bf16x8 bb[2][4];   // LDS B ping-pong

    // ================= Layer 0, half h = 0 (n in [0,256)) ==================
    #pragma unroll
    for (int at = 0; at < 2; ++at)
        #pragma unroll
        for (int bt = 0; bt < 4; ++bt)
            acc[at][bt] = (f32x4){0.f, 0.f, 0.f, 0.f};

    #pragma unroll
    for (int bt = 0; bt < 4; ++bt)
        bb[0][bt] = *(const bf16x8*)(xs + ((bt * 8 + 0) * 64 + lane) * 8);

    #pragma unroll
    for (int ks = 0; ks < 8; ++ks) {
        if (ks < 7) {
            #pragma unroll
            for (int bt = 0; bt < 4; ++bt)
                bb[(ks + 1) & 1][bt] = *(const bf16x8*)(xs + ((bt * 8 + ks + 1) * 64 + lane) * 8);
        }
        __builtin_amdgcn_s_setprio(1);
        #pragma unroll
        for (int bt = 0; bt < 4; ++bt) {
            acc[0][bt] = MFMA16(aw[ks & 3][0], bb[ks & 1][bt], acc[0][bt]);
            acc[1][bt] = MFMA16(aw[ks & 3][1], bb[ks & 1][bt], acc[1][bt]);
        }
        __builtin_amdgcn_s_setprio(0);
        // refill slot just consumed: pairs ks+4 of half-0, then half-1 pairs
        if (ks < 4) {
            aw[ks & 3][0] = *(const bf16x8*)(w0r + (ks + 4) * 32);
            aw[ks & 3][1] = *(const bf16x8*)(w0r + 16 * DIN + (ks + 4) * 32);
        } else {
            aw[ks & 3][0] = *(const bf16x8*)(w0r1 + (ks - 4) * 32);
            aw[ks & 3][1] = *(const bf16x8*)(w0r1 + 16 * DIN + (ks - 4) * 32);
        }
        __builtin_amdgcn_sched_barrier(0);
    }

    // epilogue half 0 -> granules g = bt*8 + w (lower 32 KB); xs untouched.
    // (ring holds half-1 pairs 0..3 in flight through this epilogue)
    #pragma unroll
    for (int at = 0; at < 2; ++at) {
        const int nb = w * 32 + at * 16 + 4 * l4;
        const f32x4 b4 = *(const f32x4*)(b0 + c * NH0 + nb);
        const int sub = (at * 2 + (l4 >> 1)) * 128 + l15 * 8 + 4 * (l4 & 1);
        #pragma unroll
        for (int bt = 0; bt < 4; ++bt) {
            const int g = bt * 8 + w;
            bf16x4 pk;
            #pragma unroll
            for (int r = 0; r < 4; ++r) {
                float v = acc[at][bt][r] + b4[r];
                v = v > 0.f ? v : 0.f;
                pk[r] = (__bf16)v;
            }
            *(bf16x4*)(&h0s[g * 512 + sub]) = pk;
        }
    }

    // ================= Layer 0, half h = 1 (n in [256,512)) ================
    #pragma unroll
    for (int at = 0; at < 2; ++at)
        #pragma unroll
        for (int bt = 0; bt < 4; ++bt)
            acc[at][bt] = (f32x4){0.f, 0.f, 0.f, 0.f};

    #pragma unroll
    for (int bt = 0; bt < 4; ++bt)
        bb[0][bt] = *(const bf16x8*)(xs + ((bt * 8 + 0) * 64 + lane) * 8);

    #pragma unroll
    for (int ks = 0; ks < 8; ++ks) {
        if (ks < 7) {
            #pragma unroll
            for (int bt = 0; bt < 4; ++bt)
                bb[(ks + 1) & 1][bt] = *(const bf16x8*)(xs + ((bt * 8 + ks + 1) * 64 + lane) * 8);
        }
        __builtin_amdgcn_s_setprio(1);
        #pragma unroll
        for (int bt = 0; bt < 4; ++bt) {
            acc[0][bt] = MFMA16(aw[ks & 3][0], bb[ks & 1][bt], acc[0][bt]);
            acc[1][bt] = MFMA16(aw[ks & 3][1], bb[ks & 1][bt], acc[1][bt]);
        }
        __builtin_amdgcn_s_setprio(0);
        // refill: half-1 pairs ks+4, then W1 pairs 0..3 (in flight across the
        // two barriers + epilogue below)
        if (ks < 4) {
            aw[ks & 3][0] = *(const bf16x8*)(w0r1 + (ks + 4) * 32);
            aw[ks & 3][1] = *(const bf16x8*)(w0r1 + 16 * DIN + (ks + 4) * 32);
        } else {
            aw[ks & 3][0] = *(const bf16x8*)(w1r + (ks - 4) * 32);
            aw[ks & 3][1] = *(const bf16x8*)(w1r + 16 * NH0 + (ks - 4) * 32);
        }
        __builtin_amdgcn_sched_barrier(0);
    }

    __syncthreads();   // all waves done reading xs before granules 32..63 write

    // epilogue half 1 -> granules g = 32 + bt*8 + w
    #pragma unroll
    for (int at = 0; at < 2; ++at) {
        const int nb = 256 + w * 32 + at * 16 + 4 * l4;
        const f32x4 b4 = *(const f32x4*)(b0 + c * NH0 + nb);
        const int sub = (at * 2 + (l4 >> 1)) * 128 + l15 * 8 + 4 * (l4 & 1);
        #pragma unroll
        for (int bt = 0; bt < 4; ++bt) {
            const int g = 32 + bt * 8 + w;
            bf16x4 pk;
            #pragma unroll
            for (int r = 0; r < 4; ++r) {
                float v = acc[at][bt][r] + b4[r];
                v = v > 0.f ? v : 0.f;
                pk[r] = (__bf16)v;
            }
            *(bf16x4*)(&h0s[g * 512 + sub]) = pk;
        }
    }
    __syncthreads();   // h0 complete

    // ================= Layer 1 (A=W1 rows, B=h0 granules) ===================
    // granule for (ks, nt): g = (ks>>3)*32 + nt*8 + (ks&7)
    f32x4 acc1[2][4];   // [ot][nt]
    #pragma unroll
    for (int ot = 0; ot < 2; ++ot)
        #pragma unroll
        for (int nt = 0; nt < 4; ++nt)
            acc1[ot][nt] = (f32x4){0.f, 0.f, 0.f, 0.f};

    #pragma unroll
    for (int nt = 0; nt < 4; ++nt)
        bb[0][nt] = *(const bf16x8*)(h0s + ((nt * 8 + 0) * 64 + lane) * 8);

    #pragma unroll
    for (int ks = 0; ks < 16; ++ks) {
        if (ks < 15) {
            const int kn = ks + 1;
            const int gb = (kn >> 3) * 32 + (kn & 7);
            #pragma unroll
            for (int nt = 0; nt < 4; ++nt)
                bb[kn & 1][nt] = *(const bf16x8*)(h0s + ((gb + nt * 8) * 64 + lane) * 8);
        }
        __builtin_amdgcn_s_setprio(1);
        #pragma unroll
        for (int nt = 0; nt < 4; ++nt) {
            acc1[0][nt] = MFMA16(aw[ks & 3][0], bb[ks & 1][nt], acc1[0][nt]);
            acc1[1][nt] = MFMA16(aw[ks & 3][1], bb[ks & 1][nt], acc1[1][nt]);
        }
        __builtin_amdgcn_s_setprio(0);
        if (ks < 12) {
            aw[ks & 3][0] = *(const bf16x8*)(w1r + (ks + 4) * 32);
            aw[ks & 3][1] = *(const bf16x8*)(w1r + 16 * NH0 + (ks + 4) * 32);
        }
        __builtin_amdgcn_sched_barrier(0);
    }

    // ---------------- Layer 2 ----------------------------------------------
    // acc1: o = (2w+ot)*16 + 4*l4 + r, m = nt*16 + l15
    float part[4] = {0.f, 0.f, 0.f, 0.f};
    #pragma unroll
    for (int ot = 0; ot < 2; ++ot) {
        const int ob = (2 * w + ot) * 16 + 4 * l4;
        const f32x4 b1v = *(const f32x4*)(b1 + c * NH1 + ob);
        const f32x4 w2v = *(const f32x4*)(W2 + c * NH1 + ob);
        #pragma unroll
        for (int r = 0; r < 4; ++r) {
            #pragma unroll
            for (int nt = 0; nt < 4; ++nt) {
                float v = acc1[ot][nt][r] + b1v[r];
                v = v > 0.f ? v : 0.f;
                part[nt] += v * w2v[r];
            }
        }
    }
    #pragma unroll
    for (int nt = 0; nt < 4; ++nt) {
        part[nt] += __shfl_xor(part[nt], 16, 64);
        part[nt] += __shfl_xor(part[nt], 32, 64);
    }
    if (l4 == 0) {
        #pragma unroll
        for (int nt = 0; nt < 4; ++nt)
            red[w][nt * 16 + l15] = part[nt];
    }
    __syncthreads();

    if (tid < BT) {
        float s = 0.f;
        #pragma unroll
        for (int ww = 0; ww < 8; ++ww) s += red[ww][tid];
        s += b2[c];
        out[(size_t)(row0 + tid) * CNUM + c] = s;
    }
}

// ---------------------------------------------------------------------------
// Fallback (fp32 loads, no workspace) in case ws_size < WS_NEED. BT=64 geom.
// ---------------------------------------------------------------------------
__device__ __forceinline__ bf16x8 ld_cvt8(const float* __restrict__ p) {
    f32x8 v = *(const f32x8*)p;
    bf16x8 r;
    #pragma unroll
    for (int i = 0; i < 8; ++i) r[i] = (__bf16)v[i];
    return r;
}

#define P0 (NH0 + 8)

__global__ __launch_bounds__(NTHREADS, 4)
void confounder_fused(const float* __restrict__ x,
                      const float* __restrict__ W0,
                      const float* __restrict__ b0,
                      const float* __restrict__ W1,
                      const float* __restrict__ b1,
                      const float* __restrict__ W2,
                      const float* __restrict__ b2,
                      float* __restrict__ out) {
    __shared__ __align__(16) __bf16 h0s[BT * P0];
    __shared__ float red[8][BT];

    const int c    = blockIdx.x & 7;
    const int mb   = blockIdx.x >> 3;
    const int row0 = mb * BT;
    const int tid  = threadIdx.x;
    const int w    = tid >> 6;
    const int lane = tid & 63;
    const int l15  = lane & 15;
    const int l4   = lane >> 4;

    f32x4 acc0[4][4];
    #pragma unroll
    for (int mt = 0; mt < 4; ++mt)
        #pragma unroll
        for (int nt = 0; nt < 4; ++nt)
            acc0[mt][nt] = (f32x4){0.f, 0.f, 0.f, 0.f};

    const float* xb  = x  + (size_t)(row0 + l15) * DIN + 8 * l4;
    const float* w0b = W0 + ((size_t)c * NH0 + w * 64 + l15) * DIN + 8 * l4;

    #pragma unroll
    for (int ks = 0; ks < DIN / 32; ++ks) {
        bf16x8 a[4];
        #pragma unroll
        for (int mt = 0; mt < 4; ++mt)
            a[mt] = ld_cvt8(xb + mt * 16 * DIN + ks * 32);
        #pragma unroll
        for (int nt = 0; nt < 4; ++nt) {
            bf16x8 bf = ld_cvt8(w0b + nt * 16 * DIN + ks * 32);
            #pragma unroll
            for (int mt = 0; mt < 4; ++mt)
                acc0[mt][nt] = __builtin_amdgcn_mfma_f32_16x16x32_bf16(a[mt], bf, acc0[mt][nt], 0, 0, 0);
        }
    }
    #pragma unroll
    for (int nt = 0; nt < 4; ++nt) {
        const int n    = (w * 4 + nt) * 16 + l15;
        const float bv = b0[c * NH0 + n];
        #pragma unroll
        for (int mt = 0; mt < 4; ++mt)
            #pragma unroll
            for (int r = 0; r < 4; ++r) {
                float v = acc0[mt][nt][r] + bv;
                v = v > 0.f ? v : 0.f;
                h0s[(mt * 16 + l4 * 4 + r) * P0 + n] = (__bf16)v;
            }
    }
    __syncthreads();

    f32x4 acc1[2][4];
    #pragma unroll
    for (int ot = 0; ot < 2; ++ot)
        #pragma unroll
        for (int nt = 0; nt < 4; ++nt)
            acc1[ot][nt] = (f32x4){0.f, 0.f, 0.f, 0.f};

    const float* w1b = W1 + ((size_t)c * NH1 + w * 32 + l15) * NH0 + 8 * l4;

    #pragma unroll
    for (int ks = 0; ks < NH0 / 32; ++ks) {
        bf16x8 a[2];
        #pragma unroll
        for (int ot = 0; ot < 2; ++ot)
            a[ot] = ld_cvt8(w1b + ot * 16 * NH0 + ks * 32);
        #pragma unroll
        for (int nt = 0; nt < 4; ++nt) {
            bf16x8 bf = *(const bf16x8*)(&h0s[(nt * 16 + l15) * P0 + ks * 32 + 8 * l4]);
            #pragma unroll
            for (int ot = 0; ot < 2; ++ot)
                acc1[ot][nt] = __builtin_amdgcn_mfma_f32_16x16x32_bf16(a[ot], bf, acc1[ot][nt], 0, 0, 0);
        }
    }

    float part[4] = {0.f, 0.f, 0.f, 0.f};
    #pragma unroll
    for (int ot = 0; ot < 2; ++ot)
        #pragma unroll
        for (int r = 0; r < 4; ++r) {
            const int o     = (2 * w + ot) * 16 + l4 * 4 + r;
            const float b1v = b1[c * NH1 + o];
            const float w2v = W2[c * NH1 + o];
            #pragma unroll
            for (int nt = 0; nt < 4; ++nt) {
                float v = acc1[ot][nt][r] + b1v;
                v = v > 0.f ? v : 0.f;
                part[nt] += v * w2v;
            }
        }
    #pragma unroll
    for (int nt = 0; nt < 4; ++nt) {
        part[nt] += __shfl_xor(part[nt], 16, 64);
        part[nt] += __shfl_xor(part[nt], 32, 64);
    }
    if (l4 == 0) {
        #pragma unroll
        for (int nt = 0; nt < 4; ++nt)
            red[w][nt * 16 + l15] = part[nt];
    }
    __syncthreads();

    if (tid < BT) {
        float s = 0.f;
        #pragma unroll
        for (int ww = 0; ww < 8; ++ww) s += red[ww][tid];
        s += b2[c];
        out[(size_t)(row0 + tid) * CNUM + c] = s;
    }
}

extern "C" void kernel_launch(void* const* d_in, const int* in_sizes, int n_in,
                              void* d_out, int out_size, void* d_ws, size_t ws_size,
                              hipStream_t stream) {
    const float* x  = (const float*)d_in[0];
    const float* W0 = (const float*)d_in[1];
    const float* b0 = (const float*)d_in[2];
    const float* W1 = (const float*)d_in[3];
    const float* b1 = (const float*)d_in[4];
    const float* W2 = (const float*)d_in[5];
    const float* b2 = (const float*)d_in[6];
    float* out = (float*)d_out;

    if (ws_size >= WS_NEED) {
        __bf16* ws = (__bf16*)d_ws;
        cvt_bf16<<<dim3((X_ELEMS + W0_ELEMS + W1_ELEMS) / 8 / 256), dim3(256), 0, stream>>>(x, W0, W1, ws);
        confounder_main<<<dim3((BATCH / BT) * CNUM), dim3(NTHREADS), 0, stream>>>(ws, b0, b1, W2, b2, out);
    } else {
        confounder_fused<<<dim3((BATCH / BT) * CNUM), dim3(NTHREADS), 0, stream>>>(x, W0, b0, W1, b1, W2, b2, out);
    }
}